// Round 8
// baseline (204.812 us; speedup 1.0000x reference)
//
#include <hip/hip_runtime.h>

#define NB   32
#define H    1024
#define W    1024
#define BAND 8               // output rows per block
#define NBANDS (H / BAND)    // 128 bands per image
#define NROWS 14             // input rows per block (BAND + 6 halo)
#define TOPK 200
#define NMS_THRESH 0.1f
#define HI_THRESH  0.999f    // fast-path split; exact fallback preserved
#define CAPH 32              // hi keys per band bucket (E~8)
#define LBL  384             // LDS lo buffer per block (E~167, ~+16 sigma)

typedef unsigned long long ull;
typedef float f4 __attribute__((ext_vector_type(4)));

__device__ __forceinline__ f4 fmax4(f4 a, f4 b) {
    f4 r;
    r.x = fmaxf(a.x, b.x); r.y = fmaxf(a.y, b.y);
    r.z = fmaxf(a.z, b.z); r.w = fmaxf(a.w, b.w);
    return r;
}
__device__ __forceinline__ f4 shfl_up4(f4 v) {
    f4 r;
    r.x = __shfl_up(v.x, 1); r.y = __shfl_up(v.y, 1);
    r.z = __shfl_up(v.z, 1); r.w = __shfl_up(v.w, 1);
    return r;
}
__device__ __forceinline__ f4 shfl_dn4(f4 v) {
    f4 r;
    r.x = __shfl_down(v.x, 1); r.y = __shfl_down(v.y, 1);
    r.z = __shfl_down(v.z, 1); r.w = __shfl_down(v.w, 1);
    return r;
}

// ---------------- Phase 1: 7x7 NMS, asm-forced load burst ----------------
// R3-R7 evidence: every structure lands 72-97us; warmth-invariant (114MB
// > 32MB L2, so "warm" = L3-resident, latency ~= HBM); no pipe >25% busy;
// VGPR 52-88 measured vs >=56 needed for oq[14] -> compiler ALWAYS sinks/
// rematerializes the burst (launch_bounds and sched_barrier both failed
// to stop it). Mechanism: ~2-5 serialized ~600cy loads. This version
// issues the 14 loads as `asm volatile global_load_dwordx4`:
//   - volatile asms are ordered among themselves and before the volatile
//     `s_waitcnt vmcnt(0)` -> all 14 outstanding, by construction.
//   - outputs are asm results -> RA must keep 56 VGPRs live (cannot sink).
//   - sched_barrier(0) after the waitcnt: consumers cannot hoist above
//     it (rule #18: "memory" clobber does not order register consumers).
// Everything else is byte-identical to R7 (current best, 203.8us).
__global__ __launch_bounds__(256) void peak_kernel(
    const float* __restrict__ in,
    ull* __restrict__ cand_hi,   // [NB*NBANDS][CAPH]
    ull* __restrict__ cand_lo,   // [NB*NBANDS][capl]
    int* __restrict__ cntl,      // [NB*NBANDS], clamped counts
    int* __restrict__ cnth,      // [NB*NBANDS], -1 => hi overflow -> lo path
    int capl)
{
    __shared__ f4 edge[BAND][4][2];      // 1 KB: per-wave boundary quads
    __shared__ ull lb_lo[LBL];           // 3 KB
    __shared__ ull lb_hi[CAPH];          // 256 B
    __shared__ int lc_lo, lc_hi;

    const int img  = blockIdx.y;
    const int band = blockIdx.x;
    const int R0   = band * BAND;
    const char* base = (const char*)(in + ((size_t)img << 20));
    const int t = threadIdx.x;
    const int lane = t & 63;
    const int wv   = t >> 6;

    if (t == 0) { lc_lo = 0; lc_hi = 0; }

    const int cb = t << 4;   // own quad byte offset

    // ---- asm burst: 14 independent own-quad loads, forced in-flight ----
    f4 oq[NROWS];
    const char* ap[NROWS];
    #pragma unroll
    for (int r = 0; r < NROWS; r++) {
        const int ri = min(max(R0 - 3 + r, 0), H - 1);   // exact row clamp
        ap[r] = base + ((size_t)ri << 12) + cb;
    }
    #pragma unroll
    for (int r = 0; r < NROWS; r++)
        asm volatile("global_load_dwordx4 %0, %1, off"
                     : "=v"(oq[r]) : "v"(ap[r]));
    asm volatile("s_waitcnt vmcnt(0)" ::: "memory");
    __builtin_amdgcn_sched_barrier(0);   // consumers may not hoist above

    // ---- vertical 7-max in registers; stash wave-boundary quads ----
    f4 acc[BAND];
    #pragma unroll
    for (int ro = 0; ro < BAND; ro++) {
        f4 a = fmax4(fmax4(fmax4(oq[ro], oq[ro + 1]),
                           fmax4(oq[ro + 2], oq[ro + 3])),
                     fmax4(fmax4(oq[ro + 4], oq[ro + 5]), oq[ro + 6]));
        acc[ro] = a;
        if (lane == 0)  edge[ro][wv][0] = a;
        if (lane == 63) edge[ro][wv][1] = a;
    }
    __syncthreads();   // edge quads + lc init visible

    // ---- horizontal 7-max via shuffles + peak emit ----
    #pragma unroll
    for (int ro = 0; ro < BAND; ro++) {
        f4 a  = acc[ro];
        f4 lq = shfl_up4(a);          // lane-1's quad = cols 4t-4..4t-1
        f4 rq = shfl_dn4(a);          // lane+1's quad = cols 4t+4..4t+7
        if (lane == 0) {              // cross-wave / global-left clamp
            lq = a;
            if (t != 0) lq = edge[ro][wv - 1][1];
        }
        if (lane == 63) {             // cross-wave / global-right clamp
            rq = a;
            if (t != 255) rq = edge[ro][wv + 1][0];
        }
        float S3 = a.x;
        float S2 = fmaxf(lq.w, S3);
        float S1 = fmaxf(lq.z, S2);
        float S0 = fmaxf(lq.y, S1);
        float P5 = fmaxf(a.y, a.z);
        float P6 = fmaxf(P5, a.w);
        float P7 = fmaxf(P6, rq.x);
        float P8 = fmaxf(P7, rq.y);
        float P9 = fmaxf(P8, rq.z);
        float w0 = fmaxf(S0, P6), w1 = fmaxf(S1, P7);
        float w2 = fmaxf(S2, P8), w3 = fmaxf(S3, P9);
        f4 ctr = oq[ro + 3];
        const int rg = R0 + ro;
        bool p0 = (ctr.x > NMS_THRESH) && (ctr.x == w0);
        bool p1 = (ctr.y > NMS_THRESH) && (ctr.y == w1);
        bool p2 = (ctr.z > NMS_THRESH) && (ctr.z == w2);
        bool p3 = (ctr.w > NMS_THRESH) && (ctr.w == w3);
        int cnt = (int)p0 + (int)p1 + (int)p2 + (int)p3;
        if (cnt) {                                // rare per thread-row (~8%)
            int s = atomicAdd(&lc_lo, cnt);       // LDS-scope atomic
            unsigned ib = ((unsigned)rg << 10) | ((unsigned)t << 2);
            float cv[4] = {ctr.x, ctr.y, ctr.z, ctr.w};
            bool  pp[4] = {p0, p1, p2, p3};
            #pragma unroll
            for (int j = 0; j < 4; j++) {
                if (pp[j]) {
                    ull key = ((ull)__float_as_uint(cv[j]) << 32) |
                              (ull)(0xFFFFFFFFu - (ib + j));
                    if (s < LBL) lb_lo[s] = key;
                    s++;
                    if (cv[j] > HI_THRESH) {      // ~1/20 of peaks
                        int q = atomicAdd(&lc_hi, 1);
                        if (q < CAPH) lb_hi[q] = key;
                    }
                }
            }
        }
    }

    // ---- flush: coalesced stores to this block's private bucket ----
    __syncthreads();
    const int bkt = img * NBANDS + band;
    const int nl_raw = lc_lo, nh_raw = lc_hi;
    const int nl = min(nl_raw, min(LBL, capl));
    const int nh = min(nh_raw, CAPH);
    ull* glo = cand_lo + (size_t)bkt * capl;
    for (int i = t; i < nl; i += 256) glo[i] = lb_lo[i];
    ull* ghi = cand_hi + (size_t)bkt * CAPH;
    if (t < nh) ghi[t] = lb_hi[t];
    if (t == 0) {
        cntl[bkt] = nl;
        cnth[bkt] = (nh_raw > CAPH) ? -1 : nh_raw;   // -1: force exact lo path
    }
}

// ---------------- Phase 2: per-image exact top-200 ----------------
// Byte-identical to the R3/R7-verified kernel (~17us): AND/OR prefix skip,
// early-exit radix, shuffle suffix-scan, rank-select.
__global__ __launch_bounds__(256) void topk_kernel(
    const ull* __restrict__ cand_hi,
    const ull* __restrict__ cand_lo,
    const int* __restrict__ cntl,
    const int* __restrict__ cnth,
    float* __restrict__ out,
    int capl)
{
    const int img = blockIdx.x;
    const int t = threadIdx.x;
    const int wv = t >> 6;
    const int lane = t & 63;
    __shared__ ull stage[NBANDS * CAPH];   // 32 KB: all hi keys fit
    __shared__ unsigned hist[4][256];      // wave-private histograms
    __shared__ unsigned sfx[256];
    __shared__ ull sel[256];
    __shared__ int s_ch[NBANDS], s_cl[NBANDS], s_oh[NBANDS + 1];
    __shared__ int s_ok;
    __shared__ int scnt;
    __shared__ unsigned s_pref;
    __shared__ int s_k, s_stop;
    __shared__ unsigned aW[4], oW[4], s_and, s_or, wsum[4];

    if (t == 0) { s_ok = 1; s_stop = 0; scnt = 0; }
    __syncthreads();
    if (t < NBANDS) {
        int raw = cnth[img * NBANDS + t];
        s_ch[t] = max(raw, 0);
        s_cl[t] = cntl[img * NBANDS + t];
        if (raw < 0) s_ok = 0;       // benign race: all writers store 0
    }
    __syncthreads();
    if (t == 0) {
        int a = 0;
        for (int b = 0; b < NBANDS; b++) { s_oh[b] = a; a += s_ch[b]; }
        s_oh[NBANDS] = a;
    }
    __syncthreads();
    const int nh = s_oh[NBANDS];
    const bool use_hi = (nh >= TOPK) && (s_ok != 0);

    if (use_hi) {
        int b = t >> 1, i0 = t & 1;              // 2 threads per band
        int nb = s_ch[b], ob = s_oh[b];
        const ull* p = cand_hi + (size_t)(img * NBANDS + b) * CAPH;
        for (int i = i0; i < nb; i += 2) stage[ob + i] = p[i];
    }
    __syncthreads();

    int n_tot = nh;
    if (!use_hi) {
        n_tot = 0;
        for (int b = 0; b < NBANDS; b++) n_tot += s_cl[b];
    }

    unsigned T = 0;   // value-bits threshold (partial or exact)
    if (n_tot > 256) {
        // ---- AND/OR over candidate value bits -> common high-byte prefix
        unsigned va = 0xFFFFFFFFu, vo = 0u;
        if (use_hi) {
            for (int i = t; i < nh; i += 256) {
                unsigned vb = (unsigned)(stage[i] >> 32);
                va &= vb; vo |= vb;
            }
        } else {
            for (int b = 0; b < NBANDS; b++) {
                int nb = s_cl[b];
                const ull* p = cand_lo + (size_t)(img * NBANDS + b) * capl;
                for (int i = t; i < nb; i += 256) {
                    unsigned vb = (unsigned)(p[i] >> 32);
                    va &= vb; vo |= vb;
                }
            }
        }
        #pragma unroll
        for (int off = 32; off > 0; off >>= 1) {
            va &= __shfl_xor(va, off);
            vo |= __shfl_xor(vo, off);
        }
        if (lane == 0) { aW[wv] = va; oW[wv] = vo; }
        __syncthreads();
        if (t == 0) {
            unsigned A = 0xFFFFFFFFu, O = 0u;
            for (int w = 0; w < 4; w++) { A &= aW[w]; O |= oW[w]; }
            s_and = A; s_or = O;
        }
        __syncthreads();
        const unsigned diff = s_and ^ s_or;
        int sb = 3;
        unsigned maskhi = 0u;
        while (sb >= 0 && ((diff >> (sb * 8)) & 0xFFu) == 0u) {
            maskhi |= 0xFFu << (sb * 8);
            sb--;
        }
        unsigned prefix = s_and & maskhi;

        if (sb < 0) {
            T = s_and;               // all candidate values identical
        } else {
            int kk = TOPK;
            for (int byte = sb; byte >= 0; byte--) {
                #pragma unroll
                for (int w = 0; w < 4; w++) hist[w][t] = 0;
                __syncthreads();
                const int shift = byte * 8;
                if (use_hi) {
                    for (int i = t; i < nh; i += 256) {
                        unsigned vb = (unsigned)(stage[i] >> 32);
                        if ((vb & maskhi) == prefix)
                            atomicAdd(&hist[wv][(vb >> shift) & 0xFFu], 1u);
                    }
                } else {
                    for (int b = 0; b < NBANDS; b++) {
                        int nb = s_cl[b];
                        const ull* p = cand_lo + (size_t)(img * NBANDS + b) * capl;
                        for (int i = t; i < nb; i += 256) {
                            unsigned vb = (unsigned)(p[i] >> 32);
                            if ((vb & maskhi) == prefix)
                                atomicAdd(&hist[wv][(vb >> shift) & 0xFFu], 1u);
                        }
                    }
                }
                __syncthreads();
                // suffix-scan of 256 bins: wave shuffle (2 barriers)
                unsigned v = hist[0][t] + hist[1][t] + hist[2][t] + hist[3][t];
                #pragma unroll
                for (int off = 1; off < 64; off <<= 1) {
                    unsigned u = __shfl_down(v, off);
                    if (lane + off < 64) v += u;
                }
                if (lane == 0) wsum[wv] = v;
                __syncthreads();
                unsigned add = 0;
                for (int w = wv + 1; w < 4; w++) add += wsum[w];
                unsigned myfx = v + add;         // count(matching, byte >= t)
                sfx[t] = myfx;
                __syncthreads();
                unsigned nxt = (t == 255) ? 0u : sfx[t + 1];
                if (myfx >= (unsigned)kk && nxt < (unsigned)kk) {
                    s_pref = prefix | ((unsigned)t << shift);
                    s_k = kk - (int)nxt;
                    // candidates {vb >= new partial T} = (TOPK-kk) + myfx
                    if ((TOPK - kk) + (int)myfx <= 256) s_stop = 1;
                }
                __syncthreads();
                prefix = s_pref;
                kk = s_k;
                maskhi |= (0xFFu << shift);
                if (s_stop) break;
            }
            T = prefix;
        }
    }

    __syncthreads();
    if (use_hi) {
        for (int i = t; i < nh; i += 256) {
            ull k = stage[i];
            if ((unsigned)(k >> 32) >= T) {
                int s = atomicAdd(&scnt, 1);
                if (s < 256) sel[s] = k;
            }
        }
    } else {
        for (int b = 0; b < NBANDS; b++) {
            int nb = s_cl[b];
            const ull* p = cand_lo + (size_t)(img * NBANDS + b) * capl;
            for (int i = t; i < nb; i += 256) {
                ull k = p[i];
                if ((unsigned)(k >> 32) >= T) {
                    int s = atomicAdd(&scnt, 1);
                    if (s < 256) sel[s] = k;
                }
            }
        }
    }
    __syncthreads();
    const int m = min(scnt, 256);
    ull* sorted = stage;               // stage is dead past this point
    if (t >= m) sel[t] = 0ull;
    sorted[t] = 0ull;
    __syncthreads();

    // ---- rank-select: exact descending order of unique full keys ----
    {
        ull k = sel[t];
        int rank = 0;
        for (int j = 0; j < 256; j++) rank += (sel[j] > k) ? 1 : 0;
        if (k != 0ull && rank < 256) sorted[rank] = k;
    }
    __syncthreads();

    // write: coords [NB,TOPK,2] then probs [NB,TOPK], all fp32
    if (t < TOPK) {
        ull key = sorted[t];
        float prob = 0.0f;
        unsigned row = 0, col = 0;
        if (key != 0ull) {
            prob = __uint_as_float((unsigned)(key >> 32));
            unsigned idx = 0xFFFFFFFFu - (unsigned)(key & 0xFFFFFFFFull);
            row = idx >> 10;
            col = idx & (W - 1);
        }
        size_t cbase = (size_t)img * TOPK * 2 + (size_t)t * 2;
        out[cbase + 0] = (float)row;
        out[cbase + 1] = (float)col;
        out[(size_t)NB * TOPK * 2 + (size_t)img * TOPK + t] = prob;
    }
}

extern "C" void kernel_launch(void* const* d_in, const int* in_sizes, int n_in,
                              void* d_out, int out_size, void* d_ws, size_t ws_size,
                              hipStream_t stream) {
    const float* center_map = (const float*)d_in[0];
    float* out = (float*)d_out;

    // workspace layout (counts plain-stored by peak_kernel; NO memset):
    //   [0, 16K)      : cntl[4096]
    //   [16K, 32K)    : cnth[4096]
    //   [32K, +1M)    : cand_hi[4096][CAPH]
    //   rest          : cand_lo[4096][capl]
    const int nbkt = NB * NBANDS;   // 4096
    int* cntl = (int*)d_ws;
    int* cnth = (int*)((char*)d_ws + 16384);
    ull* cand_hi = (ull*)((char*)d_ws + 32768);
    size_t hi_bytes = (size_t)nbkt * CAPH * sizeof(ull);   // 1 MB
    ull* cand_lo = (ull*)((char*)d_ws + 32768 + hi_bytes);
    size_t avail = (ws_size > 32768 + hi_bytes) ? (ws_size - 32768 - hi_bytes) : 0;
    int capl = (int)(avail / (nbkt * sizeof(ull)));
    if (capl > LBL) capl = LBL;
    if (capl < 1) capl = 1;

    dim3 gridA(NBANDS, NB);   // 128 x 32 = 4096 blocks
    peak_kernel<<<gridA, 256, 0, stream>>>(center_map, cand_hi, cand_lo,
                                           cntl, cnth, capl);

    topk_kernel<<<NB, 256, 0, stream>>>(cand_hi, cand_lo, cntl, cnth, out, capl);
}